// Round 1
// baseline (185.850 us; speedup 1.0000x reference)
//
#include <hip/hip_runtime.h>

// Erosion = 18x18 separable min-filter, SAME padding (lo=8, hi=9) with +inf,
// applied to x*0.5+0.5. Affine is monotone & exact-commuting with min, so we
// min-filter x and apply *0.5+0.5 at the end (bitwise identical).
//
// Fused single kernel: 128(w) x 32(h) output tile per 256-thread block.
//   phase 1: vertical 18-tap min (global -> regs -> tree -> LDS B[32][145])
//   phase 2: horizontal 18-tap min (LDS B -> regs -> tree -> LDS Bo[32][129])
//   phase 3: coalesced writeout of the 128x32 tile.

#define IMG_H 512
#define IMG_W 512
#define RLO 8   // pad_low  for k=18 SAME
// window for output i is input [i-8, i+9]

__device__ __forceinline__ float finf() { return __int_as_float(0x7f800000); }

// 16 windowed mins (window 18) from 33 inputs via pair/quad tree:
//   p[i] = min(x[i],x[i+1]); q[i] = min(p[i],p[i+2])  (covers 4)
//   out[j] = min(q[j], q[j+4], q[j+8], q[j+12], p[j+16])  (covers x[j..j+17])

__global__ __launch_bounds__(256, 4)
void erode_fused_22187801051678(const float* __restrict__ in,
                                float* __restrict__ out) {
    __shared__ float B[32][145];   // vertical-min results, odd stride: no bank conflicts
    __shared__ float Bo[32][129];  // staged outputs for coalesced writeback

    const int tid = threadIdx.x;
    const int w0 = blockIdx.x * 128;
    const int h0 = blockIdx.y * 32;
    const size_t plane = (size_t)blockIdx.z * (IMG_H * IMG_W);

    // ---- phase 1: vertical min. 290 units = 145 cols x 2 segs (16 out rows each)
    for (int u = tid; u < 290; u += 256) {
        int col, seg;
        if (u < 145) { col = u;       seg = 0; }
        else         { col = u - 145; seg = 1; }
        const int gw  = w0 - RLO + col;
        const bool wok = (unsigned)gw < (unsigned)IMG_W;
        const int ghb = h0 - RLO + seg * 16;

        float x[33];
#pragma unroll
        for (int i = 0; i < 33; ++i) {
            const int gh = ghb + i;
            float v = finf();
            if (wok && (unsigned)gh < (unsigned)IMG_H)
                v = in[plane + (size_t)gh * IMG_W + gw];
            x[i] = v;
        }
        float p[32];
#pragma unroll
        for (int i = 0; i < 32; ++i) p[i] = fminf(x[i], x[i + 1]);
        float q[30];
#pragma unroll
        for (int i = 0; i < 30; ++i) q[i] = fminf(p[i], p[i + 2]);
#pragma unroll
        for (int j = 0; j < 16; ++j) {
            float m = fminf(fminf(q[j], q[j + 4]), fminf(q[j + 8], q[j + 12]));
            m = fminf(m, p[j + 16]);
            B[seg * 16 + j][col] = m;
        }
    }
    __syncthreads();

    // ---- phase 2: horizontal min. exactly 256 units: row r, 16-wide chunk c8
    {
        const int r  = tid & 31;   // lanes 0..31 hit distinct rows -> stride-145 reads, conflict-free
        const int c8 = tid >> 5;   // 8 chunks of 16 outputs
        float y[33];
#pragma unroll
        for (int i = 0; i < 33; ++i) y[i] = B[r][c8 * 16 + i];
        float p[32];
#pragma unroll
        for (int i = 0; i < 32; ++i) p[i] = fminf(y[i], y[i + 1]);
        float q[30];
#pragma unroll
        for (int i = 0; i < 30; ++i) q[i] = fminf(p[i], p[i + 2]);
#pragma unroll
        for (int j = 0; j < 16; ++j) {
            float m = fminf(fminf(q[j], q[j + 4]), fminf(q[j + 8], q[j + 12]));
            m = fminf(m, p[j + 16]);
            Bo[r][c8 * 16 + j] = m * 0.5f + 0.5f;  // apply affine once, at the end
        }
    }
    __syncthreads();

    // ---- phase 3: coalesced writeout of the 128x32 tile
#pragma unroll
    for (int t = 0; t < 16; ++t) {
        const int idx = t * 256 + tid;
        const int r = idx >> 7;      // 0..31
        const int c = idx & 127;     // 0..127
        out[plane + (size_t)(h0 + r) * IMG_W + (w0 + c)] = Bo[r][c];
    }
}

extern "C" void kernel_launch(void* const* d_in, const int* in_sizes, int n_in,
                              void* d_out, int out_size, void* d_ws, size_t ws_size,
                              hipStream_t stream) {
    const float* x = (const float*)d_in[0];
    float* out = (float*)d_out;
    // planes = N*C, derived from the flat input size (512x512 images)
    const int planes = in_sizes[0] / (IMG_H * IMG_W);   // 96 for (32,3,512,512)
    dim3 grid(IMG_W / 128, IMG_H / 32, planes);
    erode_fused_22187801051678<<<grid, dim3(256), 0, stream>>>(x, out);
}